// Round 2
// baseline (312.002 us; speedup 1.0000x reference)
//
#include <hip/hip_runtime.h>
#include <hip/hip_fp16.h>

#define N_NODES 50000
#define N_EDGES 800000
#define D 128
#define N_GRAPHS 64
#define NEG_SLOPE 0.01f
#define ELLW 32      // 32 ushort slots = 64 B per node row
#define OVF_CAP 8192 // overflow pairs per branch; expected usage ~30

#define BUCKETS 196  // dst>>8 -> 196 buckets of 256 nodes
#define NPAD (BUCKETS * 256)
#define EPB 4096     // edges per phase-A block
#define BCAP 5120    // per-bucket capacity
#define XS 136       // LDS row stride (halves) for MFMA tiles

typedef _Float16 half8 __attribute__((ext_vector_type(8)));
typedef _Float16 half4 __attribute__((ext_vector_type(4)));
typedef float f32x4 __attribute__((ext_vector_type(4)));
typedef float f32x2 __attribute__((ext_vector_type(2)));

__device__ __forceinline__ int lower_bound_i(const int* __restrict__ arr, int n, int key) {
    int lo = 0, hi = n;
    while (lo < hi) {
        int mid = (lo + hi) >> 1;
        if (arr[mid] < key) lo = mid + 1; else hi = mid;
    }
    return lo;
}

// ---------------- prep: W transpose+cast, zero gcnt/ocnt/pp, per-graph node counts ----------------
__global__ __launch_bounds__(256) void k_prep(const float* __restrict__ Wa, const float* __restrict__ Wb,
                                              const float* __restrict__ Wc, const float* __restrict__ Wd,
                                              const int* __restrict__ batch1, const int* __restrict__ batch2,
                                              __half* __restrict__ WtH, int* __restrict__ gcnt,
                                              float* __restrict__ pp, int* __restrict__ cntg) {
    const float* Ws[4] = {Wa, Wb, Wc, Wd};
    const float* W = Ws[blockIdx.x];
    __half* o = WtH + (size_t)blockIdx.x * 16384;
    int t = threadIdx.x;
    for (int r = 0; r < 64; r++) {
        int e = r * 256 + t;
        int k = e >> 7, n = e & 127;
        o[n * 128 + k] = __float2half(W[k * 128 + n]);
    }
    // zero pp (2*64*128 floats) across the 4 blocks
#pragma unroll
    for (int i = 0; i < 16; i++) pp[blockIdx.x * 4096 + i * 256 + t] = 0.0f;
    if (blockIdx.x == 0) {  // zero gcnt (2*BUCKETS) + ocnt (8), contiguous
        for (int i = t; i < 2 * BUCKETS + 8; i += 256) gcnt[i] = 0;
    }
    if (blockIdx.x == 1) {  // per-graph node counts
        if (t < 64)
            cntg[t] = lower_bound_i(batch1, N_NODES, t + 1) - lower_bound_i(batch1, N_NODES, t);
        else if (t < 128)
            cntg[t] = lower_bound_i(batch2, N_NODES, (t - 64) + 1) - lower_bound_i(batch2, N_NODES, t - 64);
    }
}

// ---------------- Phase A: partition edges into dst-buckets (both branches, blockIdx.y) ----------------
__global__ __launch_bounds__(256) void k_part(const int* __restrict__ ei1, const int* __restrict__ ei2,
                                              int* __restrict__ gcnt, int2* __restrict__ bucketed) {
    const int br = blockIdx.y;
    const int* __restrict__ src = (br ? ei2 : ei1);
    const int* __restrict__ dst = src + N_EDGES;
    int* __restrict__ gc = gcnt + br * BUCKETS;
    int2* __restrict__ bk = bucketed + (size_t)br * BUCKETS * BCAP;

    __shared__ int bcnt[BUCKETS];
    __shared__ int bofs[BUCKETS];
    __shared__ int gbase[BUCKETS];
    __shared__ int sc[BUCKETS];
    __shared__ int stot;
    __shared__ int2 stage[EPB];
    const int tid = threadIdx.x;
    const int base = blockIdx.x * EPB;
    for (int b = tid; b < BUCKETS; b += 256) bcnt[b] = 0;
    __syncthreads();
    int d_[16], s_[16], p_[16];
#pragma unroll
    for (int k = 0; k < 16; k++) {
        int i = base + k * 256 + tid;
        bool v = i < N_EDGES;
        d_[k] = v ? dst[i] : -1;
        s_[k] = v ? src[i] : 0;
        p_[k] = 0;
        if (v) p_[k] = atomicAdd(&bcnt[d_[k] >> 8], 1);
    }
    __syncthreads();
    // parallel inclusive scan over bcnt (Hillis-Steele, 196 entries)
    if (tid < BUCKETS) sc[tid] = bcnt[tid];
    __syncthreads();
    for (int off = 1; off < BUCKETS; off <<= 1) {
        int v = (tid < BUCKETS && tid >= off) ? sc[tid - off] : 0;
        __syncthreads();
        if (tid < BUCKETS) sc[tid] += v;
        __syncthreads();
    }
    if (tid < BUCKETS) {
        bofs[tid] = sc[tid] - bcnt[tid];
        gbase[tid] = atomicAdd(&gc[tid], bcnt[tid]);
    }
    if (tid == BUCKETS - 1) stot = sc[tid];
    __syncthreads();
#pragma unroll
    for (int k = 0; k < 16; k++) {
        if (d_[k] >= 0) stage[bofs[d_[k] >> 8] + p_[k]] = make_int2(d_[k], s_[k]);
    }
    __syncthreads();
    int total = stot;
    for (int i = tid; i < total; i += 256) {
        int2 e = stage[i];
        int b = e.x >> 8;
        int dest = gbase[b] + (i - bofs[b]);
        if (dest < BCAP) bk[(size_t)b * BCAP + dest] = e;
    }
}

// ---------------- Phase B: build ELL tile per bucket in LDS (both branches) ----------------
__global__ __launch_bounds__(256) void k_build(const int* __restrict__ gcnt, const int2* __restrict__ bucketed,
                                               int* __restrict__ cnti, unsigned short* __restrict__ ell,
                                               int2* __restrict__ ovf, int* __restrict__ ocnt) {
    const int br = blockIdx.y;
    const int* __restrict__ gc = gcnt + br * BUCKETS;
    const int2* __restrict__ bk = bucketed + (size_t)br * BUCKETS * BCAP;
    int* __restrict__ ci = cnti + br * NPAD;
    unsigned short* __restrict__ el = ell + (size_t)br * NPAD * ELLW;
    int2* __restrict__ ov = ovf + (size_t)br * OVF_CAP;
    int* __restrict__ oc = ocnt + br;

    __shared__ unsigned short lell[256 * ELLW];
    __shared__ int lcnt[256];
    const int b = blockIdx.x, tid = threadIdx.x;
    lcnt[tid] = 0;
    __syncthreads();
    int nb = min(gc[b], BCAP);
    const int2* __restrict__ bp = bk + (size_t)b * BCAP;
    for (int i = tid; i < nb; i += 256) {
        int2 e = bp[i];
        int dl = e.x & 255;
        int p = atomicAdd(&lcnt[dl], 1);
        if (p < ELLW) {
            lell[dl * ELLW + p] = (unsigned short)e.y;
        } else {
            int o = atomicAdd(oc, 1);
            if (o < OVF_CAP) ov[o] = e;
        }
    }
    __syncthreads();
    ci[b * 256 + tid] = lcnt[tid];
    uint4* eg = (uint4*)(el + (size_t)b * 256 * ELLW);
    const uint4* elc = (const uint4*)lell;
    for (int i = tid; i < 256 * ELLW * 2 / 16; i += 256) eg[i] = elc[i];
}

// ---------------- layer-0 GEMM: H8a[N,128](fp8) = (x fp32 @ W0) * rsqrt(cnt+1), both branches ----------------
__global__ __launch_bounds__(256) void k_gemm(const float* __restrict__ x1, const float* __restrict__ x2,
                                              const __half* __restrict__ WtHall,
                                              const int* __restrict__ cnti, unsigned char* __restrict__ H8) {
    const int br = blockIdx.y;
    const float* __restrict__ x = (br ? x2 : x1);
    const __half* __restrict__ WtH = WtHall + (size_t)(br * 2 + 0) * 16384;
    const int* __restrict__ cnt = cnti + br * NPAD;
    unsigned char* __restrict__ h = H8 + (size_t)br * N_NODES * 128;

    __shared__ _Float16 Xl[64 * XS];
    __shared__ _Float16 Wt[128 * XS];
    const int tid = threadIdx.x;
    const int w = tid >> 6, lane = tid & 63;
    const int quad = lane >> 4, l16 = lane & 15;
    const int row0 = blockIdx.x * 64;

#pragma unroll
    for (int i = 0; i < 8; i++) {
        int i2 = tid + 256 * i;
        int r = i2 >> 4, cg = i2 & 15;
        *(uint4*)&Wt[r * XS + cg * 8] = ((const uint4*)WtH)[i2];
    }
#pragma unroll
    for (int i = 0; i < 8; i++) {
        int i2 = tid + 256 * i;
        int r = i2 >> 5, f4 = i2 & 31;
        float4 v = make_float4(0.f, 0.f, 0.f, 0.f);
        if (row0 + r < N_NODES) v = *(const float4*)(x + (size_t)(row0 + r) * D + f4 * 4);
        half4 hv;
        hv[0] = (_Float16)v.x; hv[1] = (_Float16)v.y; hv[2] = (_Float16)v.z; hv[3] = (_Float16)v.w;
        *(half4*)&Xl[r * XS + f4 * 4] = hv;
    }
    __syncthreads();

    half8 a[4];
#pragma unroll
    for (int kb = 0; kb < 4; kb++)
        a[kb] = *(const half8*)&Xl[(w * 16 + l16) * XS + kb * 32 + quad * 8];

    const int rbase = row0 + w * 16 + quad * 4;
    float di[4];
#pragma unroll
    for (int reg = 0; reg < 4; reg++) {
        int r = rbase + reg;
        di[reg] = (r < N_NODES) ? rsqrtf((float)cnt[r] + 1.0f) : 0.0f;
    }

    float accs[8][4];
#pragma unroll
    for (int ct = 0; ct < 8; ct++) {
        f32x4 acc = {0.f, 0.f, 0.f, 0.f};
#pragma unroll
        for (int kb = 0; kb < 4; kb++) {
            half8 b = *(const half8*)&Wt[(ct * 16 + l16) * XS + kb * 32 + quad * 8];
            acc = __builtin_amdgcn_mfma_f32_16x16x32_f16(a[kb], b, acc, 0, 0, 0);
        }
#pragma unroll
        for (int reg = 0; reg < 4; reg++) accs[ct][reg] = acc[reg] * di[reg];
    }

    __syncthreads();
    unsigned char* S = (unsigned char*)Xl;
#pragma unroll
    for (int ct = 0; ct < 8; ct++)
#pragma unroll
        for (int reg = 0; reg < 4; reg++) {
            int p = __builtin_amdgcn_cvt_pk_fp8_f32(accs[ct][reg], accs[ct][reg], 0, false);
            S[(w * 16 + quad * 4 + reg) * 128 + ct * 16 + l16] = (unsigned char)p;
        }
    __syncthreads();
#pragma unroll
    for (int i = 0; i < 2; i++) {
        int idx = tid + 256 * i;
        int r = idx >> 3, cg = idx & 7;
        if (row0 + r < N_NODES)
            ((uint4*)(h + (size_t)(row0 + r) * 128))[cg] = ((const uint4*)S)[idx];
    }
}

// ---------------- fused agg(layer0) + GEMM(layer1): H8b = (leaky(agg) @ W1) * dinv ----------------
// Each block: 64 nodes. Half-wave hw aggregates nodes row0+hw*8+t (t=0..7) into fp16 rows of Xl,
// then the standard MFMA body computes the layer-1 GEMM for those 64 rows.
__global__ __launch_bounds__(256) void k_aggemm(const int* __restrict__ cnti, const unsigned short* __restrict__ ell,
                                                const int2* __restrict__ ovf, const int* __restrict__ ocnt,
                                                const unsigned char* __restrict__ H8in,
                                                const float* __restrict__ bias1, const float* __restrict__ bias2,
                                                const __half* __restrict__ WtHall,
                                                unsigned char* __restrict__ H8out) {
    const int br = blockIdx.y;
    const int* __restrict__ cnt = cnti + br * NPAD;
    const unsigned short* __restrict__ el = ell + (size_t)br * NPAD * ELLW;
    const int2* __restrict__ ov = ovf + (size_t)br * OVF_CAP;
    const unsigned char* __restrict__ H8 = H8in + (size_t)br * N_NODES * 128;
    const float* __restrict__ bias = (br ? bias2 : bias1);
    const __half* __restrict__ WtH = WtHall + (size_t)(br * 2 + 1) * 16384;
    unsigned char* __restrict__ hout = H8out + (size_t)br * N_NODES * 128;

    __shared__ _Float16 Xl[64 * XS];
    __shared__ _Float16 Wt[128 * XS];
    const int tid = threadIdx.x;
    const int w = tid >> 6, lane = tid & 63;
    const int quad = lane >> 4, l16 = lane & 15;
    const int l32 = tid & 31;
    const int hw = tid >> 5;
    const int row0 = blockIdx.x * 64;

    // stage layer-1 weights (independent of agg)
#pragma unroll
    for (int i = 0; i < 8; i++) {
        int i2 = tid + 256 * i;
        int r = i2 >> 4, cg = i2 & 15;
        *(uint4*)&Wt[r * XS + cg * 8] = ((const uint4*)WtH)[i2];
    }

    float4 bv = ((const float4*)bias)[l32];
    for (int t = 0; t < 8; t++) {
        const int r = hw * 8 + t;
        const int node = row0 + r;
        const bool valid = node < N_NODES;
        int n = valid ? cnt[node] : 0;
        int nc = min(n, ELLW);
        int sv = 0;
        if (l32 < nc) sv = (int)el[(size_t)node * ELLW + l32];

        float4 acc[8];
        if (valid) {
            unsigned int dw = *(const unsigned int*)(H8 + (size_t)node * 128 + l32 * 4);
            f32x2 lo = __builtin_amdgcn_cvt_pk_f32_fp8((int)dw, false);
            f32x2 hi = __builtin_amdgcn_cvt_pk_f32_fp8((int)dw, true);
            acc[0] = make_float4(lo[0], lo[1], hi[0], hi[1]);  // self term
        } else {
            acc[0] = make_float4(0.f, 0.f, 0.f, 0.f);
        }
#pragma unroll
        for (int i = 1; i < 8; i++) acc[i] = make_float4(0.f, 0.f, 0.f, 0.f);

        for (int j = 0; j < nc; j += 8) {  // nc is uniform within the half-wave
            int s[8]; float wt[8];
#pragma unroll
            for (int i = 0; i < 8; i++) {
                s[i] = __shfl(sv, j + i, 32);
                wt[i] = ((j + i) < nc) ? 1.0f : 0.0f;
            }
#pragma unroll
            for (int i = 0; i < 8; i++) {
                unsigned int dw = *(const unsigned int*)(H8 + (size_t)s[i] * 128 + l32 * 4);
                f32x2 lo = __builtin_amdgcn_cvt_pk_f32_fp8((int)dw, false);
                f32x2 hi = __builtin_amdgcn_cvt_pk_f32_fp8((int)dw, true);
                acc[i].x = fmaf(wt[i], lo[0], acc[i].x);
                acc[i].y = fmaf(wt[i], lo[1], acc[i].y);
                acc[i].z = fmaf(wt[i], hi[0], acc[i].z);
                acc[i].w = fmaf(wt[i], hi[1], acc[i].w);
            }
        }
        if (n > ELLW) {  // rare overflow path
            int oc = min(ocnt[br], OVF_CAP);
            for (int o = 0; o < oc; o++) {
                int2 p = ov[o];
                if (p.x == node) {
                    unsigned int dw = *(const unsigned int*)(H8 + (size_t)p.y * 128 + l32 * 4);
                    f32x2 lo = __builtin_amdgcn_cvt_pk_f32_fp8((int)dw, false);
                    f32x2 hi = __builtin_amdgcn_cvt_pk_f32_fp8((int)dw, true);
                    acc[0].x += lo[0]; acc[0].y += lo[1]; acc[0].z += hi[0]; acc[0].w += hi[1];
                }
            }
        }
        float sx = ((acc[0].x + acc[1].x) + (acc[2].x + acc[3].x)) + ((acc[4].x + acc[5].x) + (acc[6].x + acc[7].x));
        float sy = ((acc[0].y + acc[1].y) + (acc[2].y + acc[3].y)) + ((acc[4].y + acc[5].y) + (acc[6].y + acc[7].y));
        float sz = ((acc[0].z + acc[1].z) + (acc[2].z + acc[3].z)) + ((acc[4].z + acc[5].z) + (acc[6].z + acc[7].z));
        float sw = ((acc[0].w + acc[1].w) + (acc[2].w + acc[3].w)) + ((acc[4].w + acc[5].w) + (acc[6].w + acc[7].w));
        float dv = rsqrtf((float)n + 1.0f);
        float vx = sx * dv + bv.x;
        float vy = sy * dv + bv.y;
        float vz = sz * dv + bv.z;
        float vw = sw * dv + bv.w;
        vx = vx > 0.0f ? vx : NEG_SLOPE * vx;
        vy = vy > 0.0f ? vy : NEG_SLOPE * vy;
        vz = vz > 0.0f ? vz : NEG_SLOPE * vz;
        vw = vw > 0.0f ? vw : NEG_SLOPE * vw;
        union { __half2 h2[2]; uint2 u; } up;
        if (valid) {
            up.h2[0] = __floats2half2_rn(vx, vy);
            up.h2[1] = __floats2half2_rn(vz, vw);
        } else {
            up.u = make_uint2(0u, 0u);
        }
        *(uint2*)&Xl[r * XS + l32 * 4] = up.u;  // fp16 activation row into A-tile
    }
    __syncthreads();

    // ---- layer-1 MFMA (identical to k_gemm body) ----
    half8 a[4];
#pragma unroll
    for (int kb = 0; kb < 4; kb++)
        a[kb] = *(const half8*)&Xl[(w * 16 + l16) * XS + kb * 32 + quad * 8];

    const int rbase = row0 + w * 16 + quad * 4;
    float di[4];
#pragma unroll
    for (int reg = 0; reg < 4; reg++) {
        int r = rbase + reg;
        di[reg] = (r < N_NODES) ? rsqrtf((float)cnt[r] + 1.0f) : 0.0f;
    }

    float accs[8][4];
#pragma unroll
    for (int ct = 0; ct < 8; ct++) {
        f32x4 acc = {0.f, 0.f, 0.f, 0.f};
#pragma unroll
        for (int kb = 0; kb < 4; kb++) {
            half8 b = *(const half8*)&Wt[(ct * 16 + l16) * XS + kb * 32 + quad * 8];
            acc = __builtin_amdgcn_mfma_f32_16x16x32_f16(a[kb], b, acc, 0, 0, 0);
        }
#pragma unroll
        for (int reg = 0; reg < 4; reg++) accs[ct][reg] = acc[reg] * di[reg];
    }

    __syncthreads();
    unsigned char* S = (unsigned char*)Xl;
#pragma unroll
    for (int ct = 0; ct < 8; ct++)
#pragma unroll
        for (int reg = 0; reg < 4; reg++) {
            int p = __builtin_amdgcn_cvt_pk_fp8_f32(accs[ct][reg], accs[ct][reg], 0, false);
            S[(w * 16 + quad * 4 + reg) * 128 + ct * 16 + l16] = (unsigned char)p;
        }
    __syncthreads();
#pragma unroll
    for (int i = 0; i < 2; i++) {
        int idx = tid + 256 * i;
        int r = idx >> 3, cg = idx & 7;
        if (row0 + r < N_NODES)
            ((uint4*)(hout + (size_t)(row0 + r) * 128))[cg] = ((const uint4*)S)[idx];
    }
}

// ---------------- fused agg(layer1) + mean pool: segmented LDS reduce + per-graph atomics ----------------
__global__ __launch_bounds__(256) void k_aggpool(const int* __restrict__ cnti, const unsigned short* __restrict__ ell,
                                                 const int2* __restrict__ ovf, const int* __restrict__ ocnt,
                                                 const unsigned char* __restrict__ H8all,
                                                 const float* __restrict__ bias1, const float* __restrict__ bias2,
                                                 const int* __restrict__ batch1, const int* __restrict__ batch2,
                                                 float* __restrict__ ppall) {
    const int br = blockIdx.y;
    const int* __restrict__ cnt = cnti + br * NPAD;
    const unsigned short* __restrict__ el = ell + (size_t)br * NPAD * ELLW;
    const int2* __restrict__ ov = ovf + (size_t)br * OVF_CAP;
    const unsigned char* __restrict__ H8 = H8all + (size_t)br * N_NODES * 128;
    const float* __restrict__ bias = (br ? bias2 : bias1);
    const int* __restrict__ batch = (br ? batch2 : batch1);
    float* __restrict__ pp = ppall + (size_t)br * N_GRAPHS * D;

    const int tid = threadIdx.x;
    const int l32 = tid & 31;
    const int hw = tid >> 5;
    const int node = blockIdx.x * 8 + hw;  // 8 nodes per block, always < N_NODES
    int n = cnt[node];
    int nc = min(n, ELLW);
    int sv = 0;
    if (l32 < nc) sv = (int)el[(size_t)node * ELLW + l32];
    int ncOther = __shfl(nc, (tid & 63) ^ 32, 64);
    int jmax = max(nc, ncOther);

    float4 acc[8];
    {
        unsigned int dw = *(const unsigned int*)(H8 + (size_t)node * 128 + l32 * 4);
        f32x2 lo = __builtin_amdgcn_cvt_pk_f32_fp8((int)dw, false);
        f32x2 hi = __builtin_amdgcn_cvt_pk_f32_fp8((int)dw, true);
        acc[0] = make_float4(lo[0], lo[1], hi[0], hi[1]);  // self term
    }
#pragma unroll
    for (int i = 1; i < 8; i++) acc[i] = make_float4(0.f, 0.f, 0.f, 0.f);

    for (int j = 0; j < jmax; j += 8) {
        int s[8]; float wt[8];
#pragma unroll
        for (int i = 0; i < 8; i++) {
            s[i] = __shfl(sv, j + i, 32);
            wt[i] = ((j + i) < nc) ? 1.0f : 0.0f;
        }
#pragma unroll
        for (int i = 0; i < 8; i++) {
            unsigned int dw = *(const unsigned int*)(H8 + (size_t)s[i] * 128 + l32 * 4);
            f32x2 lo = __builtin_amdgcn_cvt_pk_f32_fp8((int)dw, false);
            f32x2 hi = __builtin_amdgcn_cvt_pk_f32_fp8((int)dw, true);
            acc[i].x = fmaf(wt[i], lo[0], acc[i].x);
            acc[i].y = fmaf(wt[i], lo[1], acc[i].y);
            acc[i].z = fmaf(wt[i], hi[0], acc[i].z);
            acc[i].w = fmaf(wt[i], hi[1], acc[i].w);
        }
    }
    if (n > ELLW) {  // rare overflow path
        int oc = min(ocnt[br], OVF_CAP);
        for (int o = 0; o < oc; o++) {
            int2 p = ov[o];
            if (p.x == node) {
                unsigned int dw = *(const unsigned int*)(H8 + (size_t)p.y * 128 + l32 * 4);
                f32x2 lo = __builtin_amdgcn_cvt_pk_f32_fp8((int)dw, false);
                f32x2 hi = __builtin_amdgcn_cvt_pk_f32_fp8((int)dw, true);
                acc[0].x += lo[0]; acc[0].y += lo[1]; acc[0].z += hi[0]; acc[0].w += hi[1];
            }
        }
    }
    float sx = ((acc[0].x + acc[1].x) + (acc[2].x + acc[3].x)) + ((acc[4].x + acc[5].x) + (acc[6].x + acc[7].x));
    float sy = ((acc[0].y + acc[1].y) + (acc[2].y + acc[3].y)) + ((acc[4].y + acc[5].y) + (acc[6].y + acc[7].y));
    float sz = ((acc[0].z + acc[1].z) + (acc[2].z + acc[3].z)) + ((acc[4].z + acc[5].z) + (acc[6].z + acc[7].z));
    float sw = ((acc[0].w + acc[1].w) + (acc[2].w + acc[3].w)) + ((acc[4].w + acc[5].w) + (acc[6].w + acc[7].w));
    float dv = rsqrtf((float)n + 1.0f);
    float4 b = ((const float4*)bias)[l32];
    float vx = sx * dv + b.x;
    float vy = sy * dv + b.y;
    float vz = sz * dv + b.z;
    float vw = sw * dv + b.w;
    vx = vx > 0.0f ? vx : NEG_SLOPE * vx;
    vy = vy > 0.0f ? vy : NEG_SLOPE * vy;
    vz = vz > 0.0f ? vz : NEG_SLOPE * vz;
    vw = vw > 0.0f ? vw : NEG_SLOPE * vw;
    // round to fp16 to preserve the old ACT numeric path
    __half2 q0 = __floats2half2_rn(vx, vy);
    __half2 q1 = __floats2half2_rn(vz, vw);
    float2 f0 = __half22float2(q0);
    float2 f1 = __half22float2(q1);

    __shared__ float sacc[8][128];
    __shared__ int sg[8];
    *(float4*)&sacc[hw][l32 * 4] = make_float4(f0.x, f0.y, f1.x, f1.y);
    if (l32 == 0) sg[hw] = batch[node];
    __syncthreads();
    if (tid < 128) {  // segmented reduction over the 8 (batch-sorted) nodes
        float s = sacc[0][tid];
        int g = sg[0];
        for (int r2 = 1; r2 < 8; r2++) {
            if (sg[r2] == g) {
                s += sacc[r2][tid];
            } else {
                atomicAdd(&pp[(size_t)g * D + tid], s);
                s = sacc[r2][tid];
                g = sg[r2];
            }
        }
        atomicAdd(&pp[(size_t)g * D + tid], s);
    }
}

// ---------------- final MLP ----------------
__global__ __launch_bounds__(128) void k_mlp(const float* __restrict__ pp, const int* __restrict__ cntg,
                                             const float* __restrict__ lin1W, const float* __restrict__ lin1b,
                                             const float* __restrict__ lin2W, const float* __restrict__ lin2b,
                                             float* __restrict__ out) {
    int g = blockIdx.x;
    int c = threadIdx.x;
    __shared__ float cat[2 * D];
    cat[c] = pp[(size_t)g * D + c] / fmaxf((float)cntg[g], 1.0f);
    cat[c + D] = pp[(size_t)(N_GRAPHS + g) * D + c] / fmaxf((float)cntg[64 + g], 1.0f);
    __syncthreads();
    float acc = lin1b[c];
#pragma unroll 8
    for (int k = 0; k < 2 * D; k++) acc += cat[k] * lin1W[k * D + c];
    acc = fmaxf(acc, 0.0f);
    float v = acc * lin2W[c];
#pragma unroll
    for (int off = 32; off > 0; off >>= 1) v += __shfl_down(v, off, 64);
    __shared__ float wsum[2];
    if ((c & 63) == 0) wsum[c >> 6] = v;
    __syncthreads();
    if (c == 0) out[g] = wsum[0] + wsum[1] + lin2b[0];
}

extern "C" void kernel_launch(void* const* d_in, const int* in_sizes, int n_in,
                              void* d_out, int out_size, void* d_ws, size_t ws_size,
                              hipStream_t stream) {
    const float* x1 = (const float*)d_in[0];
    const int*   ei1 = (const int*)d_in[1];
    const int*   batch1 = (const int*)d_in[2];
    const float* x2 = (const float*)d_in[3];
    const int*   ei2 = (const int*)d_in[4];
    const int*   batch2 = (const int*)d_in[5];
    const float* W1_0 = (const float*)d_in[6];
    const float* b1_0 = (const float*)d_in[7];
    const float* W1_1 = (const float*)d_in[8];
    const float* b1_1 = (const float*)d_in[9];
    const float* W2_0 = (const float*)d_in[10];
    const float* b2_0 = (const float*)d_in[11];
    const float* W2_1 = (const float*)d_in[12];
    const float* b2_1 = (const float*)d_in[13];
    const float* lin1W = (const float*)d_in[14];
    const float* lin1b = (const float*)d_in[15];
    const float* lin2W = (const float*)d_in[16];
    const float* lin2b = (const float*)d_in[17];
    float* out = (float*)d_out;

    // ---- workspace layout ----
    __half* WtH = (__half*)d_ws;                                          // 65536 halves (128 KB)
    unsigned char* H8a = (unsigned char*)(WtH + 65536);                   // 2 * N*128 bytes
    unsigned char* H8b = H8a + 2 * (size_t)N_NODES * 128;                 // 2 * N*128 bytes
    unsigned short* ell = (unsigned short*)(H8b + 2 * (size_t)N_NODES * 128);  // 2 * NPAD*ELLW
    int2*   bucketed = (int2*)(ell + 2 * (size_t)NPAD * ELLW);            // 2 * BUCKETS*BCAP
    int*    cnti = (int*)(bucketed + 2 * (size_t)BUCKETS * BCAP);         // 2 * NPAD
    int*    gcnt = cnti + 2 * NPAD;                                       // 2 * BUCKETS (+ ocnt[8] contiguous)
    int*    ocnt = gcnt + 2 * BUCKETS;                                    // 8
    int*    cntg = ocnt + 8;                                              // 128
    int2*   ovf  = (int2*)(cntg + 128);                                   // 2 * OVF_CAP
    float*  pp   = (float*)(ovf + 2 * (size_t)OVF_CAP);                   // 2 * G * D

    dim3 b256(256);
    int partBlocks = (N_EDGES + EPB - 1) / EPB;  // 196
    int gemmBlocks = (N_NODES + 63) / 64;        // 782
    int aggBlocks  = N_NODES / 8;                // 6250

    k_prep<<<4, b256, 0, stream>>>(W1_0, W1_1, W2_0, W2_1, batch1, batch2, WtH, gcnt, pp, cntg);

    k_part  <<<dim3(partBlocks, 2), b256, 0, stream>>>(ei1, ei2, gcnt, bucketed);
    k_build <<<dim3(BUCKETS, 2),    b256, 0, stream>>>(gcnt, bucketed, cnti, ell, ovf, ocnt);

    k_gemm   <<<dim3(gemmBlocks, 2), b256, 0, stream>>>(x1, x2, WtH, cnti, H8a);
    k_aggemm <<<dim3(gemmBlocks, 2), b256, 0, stream>>>(cnti, ell, ovf, ocnt, H8a, b1_0, b2_0, WtH, H8b);
    k_aggpool<<<dim3(aggBlocks, 2),  b256, 0, stream>>>(cnti, ell, ovf, ocnt, H8b, b1_1, b2_1, batch1, batch2, pp);

    k_mlp<<<N_GRAPHS, dim3(128), 0, stream>>>(pp, cntg, lin1W, lin1b, lin2W, lin2b, out);
}

// Round 3
// 288.567 us; speedup vs baseline: 1.0812x; 1.0812x over previous
//
#include <hip/hip_runtime.h>
#include <hip/hip_fp16.h>

#define N_NODES 50000
#define N_EDGES 800000
#define D 128
#define N_GRAPHS 64
#define NEG_SLOPE 0.01f
#define ELLW 32      // 32 ushort slots = 64 B per node row
#define OVF_CAP 8192 // overflow pairs per branch; expected usage ~30

#define BUCKETS 196  // dst>>8 -> 196 buckets of 256 nodes
#define NPAD (BUCKETS * 256)
#define EPB 4096     // edges per phase-A block
#define BCAP 5120    // per-bucket capacity
#define XS 136       // LDS row stride (halves) for MFMA tiles

typedef _Float16 half8 __attribute__((ext_vector_type(8)));
typedef _Float16 half4 __attribute__((ext_vector_type(4)));
typedef float f32x4 __attribute__((ext_vector_type(4)));
typedef float f32x2 __attribute__((ext_vector_type(2)));

__device__ __forceinline__ int lower_bound_i(const int* __restrict__ arr, int n, int key) {
    int lo = 0, hi = n;
    while (lo < hi) {
        int mid = (lo + hi) >> 1;
        if (arr[mid] < key) lo = mid + 1; else hi = mid;
    }
    return lo;
}

// ---------------- prep: W transpose+cast, zero gcnt/ocnt/pp, per-graph node counts ----------------
__global__ __launch_bounds__(256) void k_prep(const float* __restrict__ Wa, const float* __restrict__ Wb,
                                              const float* __restrict__ Wc, const float* __restrict__ Wd,
                                              const int* __restrict__ batch1, const int* __restrict__ batch2,
                                              __half* __restrict__ WtH, int* __restrict__ gcnt,
                                              float* __restrict__ pp, int* __restrict__ cntg) {
    const float* Ws[4] = {Wa, Wb, Wc, Wd};
    const float* W = Ws[blockIdx.x];
    __half* o = WtH + (size_t)blockIdx.x * 16384;
    int t = threadIdx.x;
    for (int r = 0; r < 64; r++) {
        int e = r * 256 + t;
        int k = e >> 7, n = e & 127;
        o[n * 128 + k] = __float2half(W[k * 128 + n]);
    }
    // zero pp (2*64*128 floats) across the 4 blocks
#pragma unroll
    for (int i = 0; i < 16; i++) pp[blockIdx.x * 4096 + i * 256 + t] = 0.0f;
    if (blockIdx.x == 0) {  // zero gcnt (2*BUCKETS) + ocnt (8), contiguous
        for (int i = t; i < 2 * BUCKETS + 8; i += 256) gcnt[i] = 0;
    }
    if (blockIdx.x == 1) {  // per-graph node counts
        if (t < 64)
            cntg[t] = lower_bound_i(batch1, N_NODES, t + 1) - lower_bound_i(batch1, N_NODES, t);
        else if (t < 128)
            cntg[t] = lower_bound_i(batch2, N_NODES, (t - 64) + 1) - lower_bound_i(batch2, N_NODES, t - 64);
    }
}

// ---------------- Phase A: partition edges into dst-buckets (both branches, blockIdx.y) ----------------
__global__ __launch_bounds__(256) void k_part(const int* __restrict__ ei1, const int* __restrict__ ei2,
                                              int* __restrict__ gcnt, int2* __restrict__ bucketed) {
    const int br = blockIdx.y;
    const int* __restrict__ src = (br ? ei2 : ei1);
    const int* __restrict__ dst = src + N_EDGES;
    int* __restrict__ gc = gcnt + br * BUCKETS;
    int2* __restrict__ bk = bucketed + (size_t)br * BUCKETS * BCAP;

    __shared__ int bcnt[BUCKETS];
    __shared__ int bofs[BUCKETS];
    __shared__ int gbase[BUCKETS];
    __shared__ int sc[BUCKETS];
    __shared__ int stot;
    __shared__ int2 stage[EPB];
    const int tid = threadIdx.x;
    const int base = blockIdx.x * EPB;
    for (int b = tid; b < BUCKETS; b += 256) bcnt[b] = 0;
    __syncthreads();
    int d_[16], s_[16], p_[16];
#pragma unroll
    for (int k = 0; k < 16; k++) {
        int i = base + k * 256 + tid;
        bool v = i < N_EDGES;
        d_[k] = v ? dst[i] : -1;
        s_[k] = v ? src[i] : 0;
        p_[k] = 0;
        if (v) p_[k] = atomicAdd(&bcnt[d_[k] >> 8], 1);
    }
    __syncthreads();
    // parallel inclusive scan over bcnt (Hillis-Steele, 196 entries)
    if (tid < BUCKETS) sc[tid] = bcnt[tid];
    __syncthreads();
    for (int off = 1; off < BUCKETS; off <<= 1) {
        int v = (tid < BUCKETS && tid >= off) ? sc[tid - off] : 0;
        __syncthreads();
        if (tid < BUCKETS) sc[tid] += v;
        __syncthreads();
    }
    if (tid < BUCKETS) {
        bofs[tid] = sc[tid] - bcnt[tid];
        gbase[tid] = atomicAdd(&gc[tid], bcnt[tid]);
    }
    if (tid == BUCKETS - 1) stot = sc[tid];
    __syncthreads();
#pragma unroll
    for (int k = 0; k < 16; k++) {
        if (d_[k] >= 0) stage[bofs[d_[k] >> 8] + p_[k]] = make_int2(d_[k], s_[k]);
    }
    __syncthreads();
    int total = stot;
    for (int i = tid; i < total; i += 256) {
        int2 e = stage[i];
        int b = e.x >> 8;
        int dest = gbase[b] + (i - bofs[b]);
        if (dest < BCAP) bk[(size_t)b * BCAP + dest] = e;
    }
}

// ---------------- Phase B: build ELL tile per bucket in LDS (both branches) ----------------
__global__ __launch_bounds__(256) void k_build(const int* __restrict__ gcnt, const int2* __restrict__ bucketed,
                                               int* __restrict__ cnti, unsigned short* __restrict__ ell,
                                               int2* __restrict__ ovf, int* __restrict__ ocnt) {
    const int br = blockIdx.y;
    const int* __restrict__ gc = gcnt + br * BUCKETS;
    const int2* __restrict__ bk = bucketed + (size_t)br * BUCKETS * BCAP;
    int* __restrict__ ci = cnti + br * NPAD;
    unsigned short* __restrict__ el = ell + (size_t)br * NPAD * ELLW;
    int2* __restrict__ ov = ovf + (size_t)br * OVF_CAP;
    int* __restrict__ oc = ocnt + br;

    __shared__ unsigned short lell[256 * ELLW];
    __shared__ int lcnt[256];
    const int b = blockIdx.x, tid = threadIdx.x;
    lcnt[tid] = 0;
    __syncthreads();
    int nb = min(gc[b], BCAP);
    const int2* __restrict__ bp = bk + (size_t)b * BCAP;
    for (int i = tid; i < nb; i += 256) {
        int2 e = bp[i];
        int dl = e.x & 255;
        int p = atomicAdd(&lcnt[dl], 1);
        if (p < ELLW) {
            lell[dl * ELLW + p] = (unsigned short)e.y;
        } else {
            int o = atomicAdd(oc, 1);
            if (o < OVF_CAP) ov[o] = e;
        }
    }
    __syncthreads();
    ci[b * 256 + tid] = lcnt[tid];
    uint4* eg = (uint4*)(el + (size_t)b * 256 * ELLW);
    const uint4* elc = (const uint4*)lell;
    for (int i = tid; i < 256 * ELLW * 2 / 16; i += 256) eg[i] = elc[i];
}

// ---------------- MFMA GEMM: H[N,128](fp8 e4m3) = (x @ W) * rsqrt(cnt+1), both branches ----------------
template <bool FP16IN>
__global__ __launch_bounds__(256) void k_gemm(const void* __restrict__ xin1, const void* __restrict__ xin2,
                                              const __half* __restrict__ WtHall, int layer,
                                              const int* __restrict__ cnti, unsigned char* __restrict__ H8) {
    const int br = blockIdx.y;
    const void* __restrict__ xin = (br ? xin2 : xin1);
    const __half* __restrict__ WtH = WtHall + (size_t)(br * 2 + layer) * 16384;
    const int* __restrict__ cnt = cnti + br * NPAD;
    unsigned char* __restrict__ h = H8 + (size_t)br * N_NODES * 128;

    __shared__ _Float16 Xl[64 * XS];
    __shared__ _Float16 Wt[128 * XS];
    const int tid = threadIdx.x;
    const int w = tid >> 6, lane = tid & 63;
    const int quad = lane >> 4, l16 = lane & 15;
    const int row0 = blockIdx.x * 64;

#pragma unroll
    for (int i = 0; i < 8; i++) {
        int i2 = tid + 256 * i;
        int r = i2 >> 4, cg = i2 & 15;
        *(uint4*)&Wt[r * XS + cg * 8] = ((const uint4*)WtH)[i2];
    }
    if (FP16IN) {
        const __half* x = (const __half*)xin;
#pragma unroll
        for (int i = 0; i < 4; i++) {
            int i2 = tid + 256 * i;
            int r = i2 >> 4, cg = i2 & 15;
            uint4 v = make_uint4(0, 0, 0, 0);
            if (row0 + r < N_NODES) v = ((const uint4*)(x + (size_t)(row0 + r) * D))[cg];
            *(uint4*)&Xl[r * XS + cg * 8] = v;
        }
    } else {
        const float* x = (const float*)xin;
#pragma unroll
        for (int i = 0; i < 8; i++) {
            int i2 = tid + 256 * i;
            int r = i2 >> 5, f4 = i2 & 31;
            float4 v = make_float4(0.f, 0.f, 0.f, 0.f);
            if (row0 + r < N_NODES) v = *(const float4*)((const float*)x + (size_t)(row0 + r) * D + f4 * 4);
            half4 hv;
            hv[0] = (_Float16)v.x; hv[1] = (_Float16)v.y; hv[2] = (_Float16)v.z; hv[3] = (_Float16)v.w;
            *(half4*)&Xl[r * XS + f4 * 4] = hv;
        }
    }
    __syncthreads();

    half8 a[4];
#pragma unroll
    for (int kb = 0; kb < 4; kb++)
        a[kb] = *(const half8*)&Xl[(w * 16 + l16) * XS + kb * 32 + quad * 8];

    const int rbase = row0 + w * 16 + quad * 4;
    float di[4];
#pragma unroll
    for (int reg = 0; reg < 4; reg++) {
        int r = rbase + reg;
        di[reg] = (r < N_NODES) ? rsqrtf((float)cnt[r] + 1.0f) : 0.0f;
    }

    float accs[8][4];
#pragma unroll
    for (int ct = 0; ct < 8; ct++) {
        f32x4 acc = {0.f, 0.f, 0.f, 0.f};
#pragma unroll
        for (int kb = 0; kb < 4; kb++) {
            half8 b = *(const half8*)&Wt[(ct * 16 + l16) * XS + kb * 32 + quad * 8];
            acc = __builtin_amdgcn_mfma_f32_16x16x32_f16(a[kb], b, acc, 0, 0, 0);
        }
#pragma unroll
        for (int reg = 0; reg < 4; reg++) accs[ct][reg] = acc[reg] * di[reg];
    }

    // fp8 epilogue: stage 64x128 bytes in LDS (reuse Xl), then coalesced 16B stores
    __syncthreads();
    unsigned char* S = (unsigned char*)Xl;
#pragma unroll
    for (int ct = 0; ct < 8; ct++)
#pragma unroll
        for (int reg = 0; reg < 4; reg++) {
            int p = __builtin_amdgcn_cvt_pk_fp8_f32(accs[ct][reg], accs[ct][reg], 0, false);
            S[(w * 16 + quad * 4 + reg) * 128 + ct * 16 + l16] = (unsigned char)p;
        }
    __syncthreads();
#pragma unroll
    for (int i = 0; i < 2; i++) {
        int idx = tid + 256 * i;
        int r = idx >> 3, cg = idx & 7;
        if (row0 + r < N_NODES)
            ((uint4*)(h + (size_t)(row0 + r) * 128))[cg] = ((const uint4*)S)[idx];
    }
}

// ---------------- ELL aggregation (layer 0): high-occupancy gather, writes fp16 ACT ----------------
// out(fp16)[d] = leaky( dinv[d] * (H[d] + sum H[src]) + bias )
__global__ __launch_bounds__(256) void k_agg(const int* __restrict__ cnti, const unsigned short* __restrict__ ell,
                                             const int2* __restrict__ ovf, const int* __restrict__ ocnt,
                                             const unsigned char* __restrict__ H8all, const float* __restrict__ bias1,
                                             const float* __restrict__ bias2, __half* __restrict__ ACT) {
    const int br = blockIdx.y;
    const int* __restrict__ cnt = cnti + br * NPAD;
    const unsigned short* __restrict__ el = ell + (size_t)br * NPAD * ELLW;
    const int2* __restrict__ ov = ovf + (size_t)br * OVF_CAP;
    const unsigned char* __restrict__ H8 = H8all + (size_t)br * N_NODES * 128;
    const float* __restrict__ bias = (br ? bias2 : bias1);
    __half* __restrict__ out = ACT + (size_t)br * N_NODES * D;

    const int tid = threadIdx.x;
    const int l32 = tid & 31;                 // lane within half-wave
    const int node = blockIdx.x * 8 + (tid >> 5);  // 8 halves per block
    int n = cnt[node];
    int nc = min(n, ELLW);
    int sv = 0;
    if (l32 < nc) sv = (int)el[(size_t)node * ELLW + l32];
    int ncOther = __shfl(nc, (tid & 63) ^ 32, 64);
    int jmax = max(nc, ncOther);

    float4 acc[8];
    {
        unsigned int dw = *(const unsigned int*)(H8 + (size_t)node * 128 + l32 * 4);
        f32x2 lo = __builtin_amdgcn_cvt_pk_f32_fp8((int)dw, false);
        f32x2 hi = __builtin_amdgcn_cvt_pk_f32_fp8((int)dw, true);
        acc[0] = make_float4(lo[0], lo[1], hi[0], hi[1]);  // self term
    }
#pragma unroll
    for (int i = 1; i < 8; i++) acc[i] = make_float4(0.f, 0.f, 0.f, 0.f);

    for (int j = 0; j < jmax; j += 8) {
        int s[8]; float w[8];
#pragma unroll
        for (int i = 0; i < 8; i++) {
            s[i] = __shfl(sv, j + i, 32);
            w[i] = ((j + i) < nc) ? 1.0f : 0.0f;
        }
#pragma unroll
        for (int i = 0; i < 8; i++) {
            unsigned int dw = *(const unsigned int*)(H8 + (size_t)s[i] * 128 + l32 * 4);
            f32x2 lo = __builtin_amdgcn_cvt_pk_f32_fp8((int)dw, false);
            f32x2 hi = __builtin_amdgcn_cvt_pk_f32_fp8((int)dw, true);
            acc[i].x = fmaf(w[i], lo[0], acc[i].x);
            acc[i].y = fmaf(w[i], lo[1], acc[i].y);
            acc[i].z = fmaf(w[i], hi[0], acc[i].z);
            acc[i].w = fmaf(w[i], hi[1], acc[i].w);
        }
    }
    if (n > ELLW) {  // rare overflow path
        int oc = min(ocnt[br], OVF_CAP);
        for (int o = 0; o < oc; o++) {
            int2 p = ov[o];
            if (p.x == node) {
                unsigned int dw = *(const unsigned int*)(H8 + (size_t)p.y * 128 + l32 * 4);
                f32x2 lo = __builtin_amdgcn_cvt_pk_f32_fp8((int)dw, false);
                f32x2 hi = __builtin_amdgcn_cvt_pk_f32_fp8((int)dw, true);
                acc[0].x += lo[0]; acc[0].y += lo[1]; acc[0].z += hi[0]; acc[0].w += hi[1];
            }
        }
    }
    float sx = ((acc[0].x + acc[1].x) + (acc[2].x + acc[3].x)) + ((acc[4].x + acc[5].x) + (acc[6].x + acc[7].x));
    float sy = ((acc[0].y + acc[1].y) + (acc[2].y + acc[3].y)) + ((acc[4].y + acc[5].y) + (acc[6].y + acc[7].y));
    float sz = ((acc[0].z + acc[1].z) + (acc[2].z + acc[3].z)) + ((acc[4].z + acc[5].z) + (acc[6].z + acc[7].z));
    float sw = ((acc[0].w + acc[1].w) + (acc[2].w + acc[3].w)) + ((acc[4].w + acc[5].w) + (acc[6].w + acc[7].w));
    float dv = rsqrtf((float)n + 1.0f);
    float4 b = ((const float4*)bias)[l32];
    float vx = sx * dv + b.x;
    float vy = sy * dv + b.y;
    float vz = sz * dv + b.z;
    float vw = sw * dv + b.w;
    vx = vx > 0.0f ? vx : NEG_SLOPE * vx;
    vy = vy > 0.0f ? vy : NEG_SLOPE * vy;
    vz = vz > 0.0f ? vz : NEG_SLOPE * vz;
    vw = vw > 0.0f ? vw : NEG_SLOPE * vw;
    union { __half2 h2[2]; uint2 u; } up;
    up.h2[0] = __floats2half2_rn(vx, vy);
    up.h2[1] = __floats2half2_rn(vz, vw);
    *(uint2*)(out + (size_t)node * 128 + l32 * 4) = up.u;
}

// ---------------- fused agg(layer1) + mean pool: segmented LDS reduce + per-graph atomics ----------------
__global__ __launch_bounds__(256) void k_aggpool(const int* __restrict__ cnti, const unsigned short* __restrict__ ell,
                                                 const int2* __restrict__ ovf, const int* __restrict__ ocnt,
                                                 const unsigned char* __restrict__ H8all,
                                                 const float* __restrict__ bias1, const float* __restrict__ bias2,
                                                 const int* __restrict__ batch1, const int* __restrict__ batch2,
                                                 float* __restrict__ ppall) {
    const int br = blockIdx.y;
    const int* __restrict__ cnt = cnti + br * NPAD;
    const unsigned short* __restrict__ el = ell + (size_t)br * NPAD * ELLW;
    const int2* __restrict__ ov = ovf + (size_t)br * OVF_CAP;
    const unsigned char* __restrict__ H8 = H8all + (size_t)br * N_NODES * 128;
    const float* __restrict__ bias = (br ? bias2 : bias1);
    const int* __restrict__ batch = (br ? batch2 : batch1);
    float* __restrict__ pp = ppall + (size_t)br * N_GRAPHS * D;

    const int tid = threadIdx.x;
    const int l32 = tid & 31;
    const int hw = tid >> 5;
    const int node = blockIdx.x * 8 + hw;  // 8 nodes per block, always < N_NODES
    int n = cnt[node];
    int nc = min(n, ELLW);
    int sv = 0;
    if (l32 < nc) sv = (int)el[(size_t)node * ELLW + l32];
    int ncOther = __shfl(nc, (tid & 63) ^ 32, 64);
    int jmax = max(nc, ncOther);

    float4 acc[8];
    {
        unsigned int dw = *(const unsigned int*)(H8 + (size_t)node * 128 + l32 * 4);
        f32x2 lo = __builtin_amdgcn_cvt_pk_f32_fp8((int)dw, false);
        f32x2 hi = __builtin_amdgcn_cvt_pk_f32_fp8((int)dw, true);
        acc[0] = make_float4(lo[0], lo[1], hi[0], hi[1]);  // self term
    }
#pragma unroll
    for (int i = 1; i < 8; i++) acc[i] = make_float4(0.f, 0.f, 0.f, 0.f);

    for (int j = 0; j < jmax; j += 8) {
        int s[8]; float wt[8];
#pragma unroll
        for (int i = 0; i < 8; i++) {
            s[i] = __shfl(sv, j + i, 32);
            wt[i] = ((j + i) < nc) ? 1.0f : 0.0f;
        }
#pragma unroll
        for (int i = 0; i < 8; i++) {
            unsigned int dw = *(const unsigned int*)(H8 + (size_t)s[i] * 128 + l32 * 4);
            f32x2 lo = __builtin_amdgcn_cvt_pk_f32_fp8((int)dw, false);
            f32x2 hi = __builtin_amdgcn_cvt_pk_f32_fp8((int)dw, true);
            acc[i].x = fmaf(wt[i], lo[0], acc[i].x);
            acc[i].y = fmaf(wt[i], lo[1], acc[i].y);
            acc[i].z = fmaf(wt[i], hi[0], acc[i].z);
            acc[i].w = fmaf(wt[i], hi[1], acc[i].w);
        }
    }
    if (n > ELLW) {  // rare overflow path
        int oc = min(ocnt[br], OVF_CAP);
        for (int o = 0; o < oc; o++) {
            int2 p = ov[o];
            if (p.x == node) {
                unsigned int dw = *(const unsigned int*)(H8 + (size_t)p.y * 128 + l32 * 4);
                f32x2 lo = __builtin_amdgcn_cvt_pk_f32_fp8((int)dw, false);
                f32x2 hi = __builtin_amdgcn_cvt_pk_f32_fp8((int)dw, true);
                acc[0].x += lo[0]; acc[0].y += lo[1]; acc[0].z += hi[0]; acc[0].w += hi[1];
            }
        }
    }
    float sx = ((acc[0].x + acc[1].x) + (acc[2].x + acc[3].x)) + ((acc[4].x + acc[5].x) + (acc[6].x + acc[7].x));
    float sy = ((acc[0].y + acc[1].y) + (acc[2].y + acc[3].y)) + ((acc[4].y + acc[5].y) + (acc[6].y + acc[7].y));
    float sz = ((acc[0].z + acc[1].z) + (acc[2].z + acc[3].z)) + ((acc[4].z + acc[5].z) + (acc[6].z + acc[7].z));
    float sw = ((acc[0].w + acc[1].w) + (acc[2].w + acc[3].w)) + ((acc[4].w + acc[5].w) + (acc[6].w + acc[7].w));
    float dv = rsqrtf((float)n + 1.0f);
    float4 b = ((const float4*)bias)[l32];
    float vx = sx * dv + b.x;
    float vy = sy * dv + b.y;
    float vz = sz * dv + b.z;
    float vw = sw * dv + b.w;
    vx = vx > 0.0f ? vx : NEG_SLOPE * vx;
    vy = vy > 0.0f ? vy : NEG_SLOPE * vy;
    vz = vz > 0.0f ? vz : NEG_SLOPE * vz;
    vw = vw > 0.0f ? vw : NEG_SLOPE * vw;
    // round to fp16 to preserve the old ACT numeric path
    __half2 q0 = __floats2half2_rn(vx, vy);
    __half2 q1 = __floats2half2_rn(vz, vw);
    float2 f0 = __half22float2(q0);
    float2 f1 = __half22float2(q1);

    __shared__ float sacc[8][128];
    __shared__ int sg[8];
    *(float4*)&sacc[hw][l32 * 4] = make_float4(f0.x, f0.y, f1.x, f1.y);
    if (l32 == 0) sg[hw] = batch[node];
    __syncthreads();
    if (tid < 128) {  // segmented reduction over the 8 (batch-sorted) nodes
        float s = sacc[0][tid];
        int g = sg[0];
        for (int r2 = 1; r2 < 8; r2++) {
            if (sg[r2] == g) {
                s += sacc[r2][tid];
            } else {
                atomicAdd(&pp[(size_t)g * D + tid], s);
                s = sacc[r2][tid];
                g = sg[r2];
            }
        }
        atomicAdd(&pp[(size_t)g * D + tid], s);
    }
}

// ---------------- final MLP ----------------
__global__ __launch_bounds__(128) void k_mlp(const float* __restrict__ pp, const int* __restrict__ cntg,
                                             const float* __restrict__ lin1W, const float* __restrict__ lin1b,
                                             const float* __restrict__ lin2W, const float* __restrict__ lin2b,
                                             float* __restrict__ out) {
    int g = blockIdx.x;
    int c = threadIdx.x;
    __shared__ float cat[2 * D];
    cat[c] = pp[(size_t)g * D + c] / fmaxf((float)cntg[g], 1.0f);
    cat[c + D] = pp[(size_t)(N_GRAPHS + g) * D + c] / fmaxf((float)cntg[64 + g], 1.0f);
    __syncthreads();
    float acc = lin1b[c];
#pragma unroll 8
    for (int k = 0; k < 2 * D; k++) acc += cat[k] * lin1W[k * D + c];
    acc = fmaxf(acc, 0.0f);
    float v = acc * lin2W[c];
#pragma unroll
    for (int off = 32; off > 0; off >>= 1) v += __shfl_down(v, off, 64);
    __shared__ float wsum[2];
    if ((c & 63) == 0) wsum[c >> 6] = v;
    __syncthreads();
    if (c == 0) out[g] = wsum[0] + wsum[1] + lin2b[0];
}

extern "C" void kernel_launch(void* const* d_in, const int* in_sizes, int n_in,
                              void* d_out, int out_size, void* d_ws, size_t ws_size,
                              hipStream_t stream) {
    const float* x1 = (const float*)d_in[0];
    const int*   ei1 = (const int*)d_in[1];
    const int*   batch1 = (const int*)d_in[2];
    const float* x2 = (const float*)d_in[3];
    const int*   ei2 = (const int*)d_in[4];
    const int*   batch2 = (const int*)d_in[5];
    const float* W1_0 = (const float*)d_in[6];
    const float* b1_0 = (const float*)d_in[7];
    const float* W1_1 = (const float*)d_in[8];
    const float* b1_1 = (const float*)d_in[9];
    const float* W2_0 = (const float*)d_in[10];
    const float* b2_0 = (const float*)d_in[11];
    const float* W2_1 = (const float*)d_in[12];
    const float* b2_1 = (const float*)d_in[13];
    const float* lin1W = (const float*)d_in[14];
    const float* lin1b = (const float*)d_in[15];
    const float* lin2W = (const float*)d_in[16];
    const float* lin2b = (const float*)d_in[17];
    float* out = (float*)d_out;

    // ---- workspace layout ----
    __half* WtH = (__half*)d_ws;                                          // 65536 halves (128 KB)
    __half* ACT = WtH + 65536;                                            // 2 * N*D halves
    unsigned char* H8a = (unsigned char*)(ACT + 2 * (size_t)N_NODES * D); // 2 * N*128 bytes
    unsigned char* H8b = H8a + 2 * (size_t)N_NODES * 128;                 // 2 * N*128 bytes
    unsigned short* ell = (unsigned short*)(H8b + 2 * (size_t)N_NODES * 128);  // 2 * NPAD*ELLW
    int2*   bucketed = (int2*)(ell + 2 * (size_t)NPAD * ELLW);            // 2 * BUCKETS*BCAP
    int*    cnti = (int*)(bucketed + 2 * (size_t)BUCKETS * BCAP);         // 2 * NPAD
    int*    gcnt = cnti + 2 * NPAD;                                       // 2 * BUCKETS (+ ocnt[8] contiguous)
    int*    ocnt = gcnt + 2 * BUCKETS;                                    // 8
    int*    cntg = ocnt + 8;                                              // 128
    int2*   ovf  = (int2*)(cntg + 128);                                   // 2 * OVF_CAP
    float*  pp   = (float*)(ovf + 2 * (size_t)OVF_CAP);                   // 2 * G * D

    dim3 b256(256);
    int partBlocks = (N_EDGES + EPB - 1) / EPB;  // 196
    int gemmBlocks = (N_NODES + 63) / 64;        // 782
    int aggBlocks  = N_NODES / 8;                // 6250

    k_prep<<<4, b256, 0, stream>>>(W1_0, W1_1, W2_0, W2_1, batch1, batch2, WtH, gcnt, pp, cntg);

    k_part  <<<dim3(partBlocks, 2), b256, 0, stream>>>(ei1, ei2, gcnt, bucketed);
    k_build <<<dim3(BUCKETS, 2),    b256, 0, stream>>>(gcnt, bucketed, cnti, ell, ovf, ocnt);

    k_gemm<false><<<dim3(gemmBlocks, 2), b256, 0, stream>>>(x1, x2, WtH, 0, cnti, H8a);
    k_agg        <<<dim3(aggBlocks, 2),  b256, 0, stream>>>(cnti, ell, ovf, ocnt, H8a, b1_0, b2_0, ACT);
    k_gemm<true> <<<dim3(gemmBlocks, 2), b256, 0, stream>>>(ACT, ACT + (size_t)N_NODES * D, WtH, 1, cnti, H8b);
    k_aggpool    <<<dim3(aggBlocks, 2),  b256, 0, stream>>>(cnti, ell, ovf, ocnt, H8b, b1_1, b2_1, batch1, batch2, pp);

    k_mlp<<<N_GRAPHS, dim3(128), 0, stream>>>(pp, cntg, lin1W, lin1b, lin2W, lin2b, out);
}

// Round 4
// 277.323 us; speedup vs baseline: 1.1251x; 1.0405x over previous
//
#include <hip/hip_runtime.h>
#include <hip/hip_fp16.h>

#define N_NODES 50000
#define N_EDGES 800000
#define D 128
#define N_GRAPHS 64
#define NEG_SLOPE 0.01f
#define ELLW 32      // 32 ushort slots = 64 B per node row
#define OVF_CAP 8192 // overflow pairs per branch; expected usage ~30

#define BUCKETS 196  // dst>>8 -> 196 buckets of 256 nodes
#define NPAD (BUCKETS * 256)
#define EPB 2048     // edges per phase-A block (2048 -> 782 blocks, 3/CU)
#define BCAP 5120    // per-bucket capacity
#define XS 136       // LDS row stride (halves) for MFMA tiles

typedef _Float16 half8 __attribute__((ext_vector_type(8)));
typedef _Float16 half4 __attribute__((ext_vector_type(4)));
typedef float f32x4 __attribute__((ext_vector_type(4)));
typedef float f32x2 __attribute__((ext_vector_type(2)));

__device__ __forceinline__ int lower_bound_i(const int* __restrict__ arr, int n, int key) {
    int lo = 0, hi = n;
    while (lo < hi) {
        int mid = (lo + hi) >> 1;
        if (arr[mid] < key) lo = mid + 1; else hi = mid;
    }
    return lo;
}

// ---------------- prep: W transpose+cast, zero gcnt/ocnt/pp, per-graph node counts ----------------
__global__ __launch_bounds__(256) void k_prep(const float* __restrict__ Wa, const float* __restrict__ Wb,
                                              const float* __restrict__ Wc, const float* __restrict__ Wd,
                                              const int* __restrict__ batch1, const int* __restrict__ batch2,
                                              __half* __restrict__ WtH, int* __restrict__ gcnt,
                                              float* __restrict__ pp, int* __restrict__ cntg) {
    const float* Ws[4] = {Wa, Wb, Wc, Wd};
    const float* W = Ws[blockIdx.x];
    __half* o = WtH + (size_t)blockIdx.x * 16384;
    int t = threadIdx.x;
    for (int r = 0; r < 64; r++) {
        int e = r * 256 + t;
        int k = e >> 7, n = e & 127;
        o[n * 128 + k] = __float2half(W[k * 128 + n]);
    }
    // zero pp (2*64*128 floats) across the 4 blocks
#pragma unroll
    for (int i = 0; i < 16; i++) pp[blockIdx.x * 4096 + i * 256 + t] = 0.0f;
    if (blockIdx.x == 0) {  // zero gcnt (2*BUCKETS) + ocnt (8), contiguous
        for (int i = t; i < 2 * BUCKETS + 8; i += 256) gcnt[i] = 0;
    }
    if (blockIdx.x == 1) {  // per-graph node counts
        if (t < 64)
            cntg[t] = lower_bound_i(batch1, N_NODES, t + 1) - lower_bound_i(batch1, N_NODES, t);
        else if (t < 128)
            cntg[t] = lower_bound_i(batch2, N_NODES, (t - 64) + 1) - lower_bound_i(batch2, N_NODES, t - 64);
    }
}

// ---------------- Phase A: partition edges into dst-buckets (1-D grid, branch = parity) ----------------
__global__ __launch_bounds__(256) void k_part(const int* __restrict__ ei1, const int* __restrict__ ei2,
                                              int* __restrict__ gcnt, int2* __restrict__ bucketed) {
    const int br = blockIdx.x & 1;
    const int blk = blockIdx.x >> 1;
    const int* __restrict__ src = (br ? ei2 : ei1);
    const int* __restrict__ dst = src + N_EDGES;
    int* __restrict__ gc = gcnt + br * BUCKETS;
    int2* __restrict__ bk = bucketed + (size_t)br * BUCKETS * BCAP;

    __shared__ int bcnt[BUCKETS];
    __shared__ int bofs[BUCKETS];
    __shared__ int gbase[BUCKETS];
    __shared__ int sc[BUCKETS];
    __shared__ int stot;
    __shared__ int2 stage[EPB];
    const int tid = threadIdx.x;
    const int base = blk * EPB;
    for (int b = tid; b < BUCKETS; b += 256) bcnt[b] = 0;
    __syncthreads();
    int d_[8], s_[8], p_[8];
#pragma unroll
    for (int k = 0; k < 8; k++) {
        int i = base + k * 256 + tid;
        bool v = i < N_EDGES;
        d_[k] = v ? dst[i] : -1;
        s_[k] = v ? src[i] : 0;
        p_[k] = 0;
        if (v) p_[k] = atomicAdd(&bcnt[d_[k] >> 8], 1);
    }
    __syncthreads();
    // parallel inclusive scan over bcnt (Hillis-Steele, 196 entries)
    if (tid < BUCKETS) sc[tid] = bcnt[tid];
    __syncthreads();
    for (int off = 1; off < BUCKETS; off <<= 1) {
        int v = (tid < BUCKETS && tid >= off) ? sc[tid - off] : 0;
        __syncthreads();
        if (tid < BUCKETS) sc[tid] += v;
        __syncthreads();
    }
    if (tid < BUCKETS) {
        bofs[tid] = sc[tid] - bcnt[tid];
        gbase[tid] = atomicAdd(&gc[tid], bcnt[tid]);
    }
    if (tid == BUCKETS - 1) stot = sc[tid];
    __syncthreads();
#pragma unroll
    for (int k = 0; k < 8; k++) {
        if (d_[k] >= 0) stage[bofs[d_[k] >> 8] + p_[k]] = make_int2(d_[k], s_[k]);
    }
    __syncthreads();
    int total = stot;
    for (int i = tid; i < total; i += 256) {
        int2 e = stage[i];
        int b = e.x >> 8;
        int dest = gbase[b] + (i - bofs[b]);
        if (dest < BCAP) bk[(size_t)b * BCAP + dest] = e;
    }
}

// ---------------- Phase B: build ELL tile per bucket in LDS (1-D grid, branch = parity) ----------------
__global__ __launch_bounds__(256) void k_build(const int* __restrict__ gcnt, const int2* __restrict__ bucketed,
                                               int* __restrict__ cnti, unsigned short* __restrict__ ell,
                                               int2* __restrict__ ovf, int* __restrict__ ocnt) {
    const int br = blockIdx.x & 1;
    const int b = blockIdx.x >> 1;
    const int* __restrict__ gc = gcnt + br * BUCKETS;
    const int2* __restrict__ bk = bucketed + (size_t)br * BUCKETS * BCAP;
    int* __restrict__ ci = cnti + br * NPAD;
    unsigned short* __restrict__ el = ell + (size_t)br * NPAD * ELLW;
    int2* __restrict__ ov = ovf + (size_t)br * OVF_CAP;
    int* __restrict__ oc = ocnt + br;

    __shared__ unsigned short lell[256 * ELLW];
    __shared__ int lcnt[256];
    const int tid = threadIdx.x;
    lcnt[tid] = 0;
    // zero the ELL tile: unused slots must hold index 0 (valid row), since the
    // gather kernels now read raw slots and mask by weight (garbage fp8 could be NaN).
#pragma unroll
    for (int i = 0; i < 4; i++) ((uint4*)lell)[tid + 256 * i] = make_uint4(0u, 0u, 0u, 0u);
    __syncthreads();
    int nb = min(gc[b], BCAP);
    const int2* __restrict__ bp = bk + (size_t)b * BCAP;
    for (int i = tid; i < nb; i += 256) {
        int2 e = bp[i];
        int dl = e.x & 255;
        int p = atomicAdd(&lcnt[dl], 1);
        if (p < ELLW) {
            lell[dl * ELLW + p] = (unsigned short)e.y;
        } else {
            int o = atomicAdd(oc, 1);
            if (o < OVF_CAP) ov[o] = e;
        }
    }
    __syncthreads();
    ci[b * 256 + tid] = lcnt[tid];
    uint4* eg = (uint4*)(el + (size_t)b * 256 * ELLW);
    const uint4* elc = (const uint4*)lell;
    for (int i = tid; i < 256 * ELLW * 2 / 16; i += 256) eg[i] = elc[i];
}

// ---------------- MFMA GEMM: H[N,128](fp8 e4m3) = (x @ W) * rsqrt(cnt+1), both branches ----------------
template <bool FP16IN>
__global__ __launch_bounds__(256) void k_gemm(const void* __restrict__ xin1, const void* __restrict__ xin2,
                                              const __half* __restrict__ WtHall, int layer,
                                              const int* __restrict__ cnti, unsigned char* __restrict__ H8) {
    const int br = blockIdx.y;
    const void* __restrict__ xin = (br ? xin2 : xin1);
    const __half* __restrict__ WtH = WtHall + (size_t)(br * 2 + layer) * 16384;
    const int* __restrict__ cnt = cnti + br * NPAD;
    unsigned char* __restrict__ h = H8 + (size_t)br * N_NODES * 128;

    __shared__ _Float16 Xl[64 * XS];
    __shared__ _Float16 Wt[128 * XS];
    const int tid = threadIdx.x;
    const int w = tid >> 6, lane = tid & 63;
    const int quad = lane >> 4, l16 = lane & 15;
    const int row0 = blockIdx.x * 64;

#pragma unroll
    for (int i = 0; i < 8; i++) {
        int i2 = tid + 256 * i;
        int r = i2 >> 4, cg = i2 & 15;
        *(uint4*)&Wt[r * XS + cg * 8] = ((const uint4*)WtH)[i2];
    }
    if (FP16IN) {
        const __half* x = (const __half*)xin;
#pragma unroll
        for (int i = 0; i < 4; i++) {
            int i2 = tid + 256 * i;
            int r = i2 >> 4, cg = i2 & 15;
            uint4 v = make_uint4(0, 0, 0, 0);
            if (row0 + r < N_NODES) v = ((const uint4*)(x + (size_t)(row0 + r) * D))[cg];
            *(uint4*)&Xl[r * XS + cg * 8] = v;
        }
    } else {
        const float* x = (const float*)xin;
#pragma unroll
        for (int i = 0; i < 8; i++) {
            int i2 = tid + 256 * i;
            int r = i2 >> 5, f4 = i2 & 31;
            float4 v = make_float4(0.f, 0.f, 0.f, 0.f);
            if (row0 + r < N_NODES) v = *(const float4*)((const float*)x + (size_t)(row0 + r) * D + f4 * 4);
            half4 hv;
            hv[0] = (_Float16)v.x; hv[1] = (_Float16)v.y; hv[2] = (_Float16)v.z; hv[3] = (_Float16)v.w;
            *(half4*)&Xl[r * XS + f4 * 4] = hv;
        }
    }
    __syncthreads();

    half8 a[4];
#pragma unroll
    for (int kb = 0; kb < 4; kb++)
        a[kb] = *(const half8*)&Xl[(w * 16 + l16) * XS + kb * 32 + quad * 8];

    const int rbase = row0 + w * 16 + quad * 4;
    float di[4];
#pragma unroll
    for (int reg = 0; reg < 4; reg++) {
        int r = rbase + reg;
        di[reg] = (r < N_NODES) ? rsqrtf((float)cnt[r] + 1.0f) : 0.0f;
    }

    float accs[8][4];
#pragma unroll
    for (int ct = 0; ct < 8; ct++) {
        f32x4 acc = {0.f, 0.f, 0.f, 0.f};
#pragma unroll
        for (int kb = 0; kb < 4; kb++) {
            half8 b = *(const half8*)&Wt[(ct * 16 + l16) * XS + kb * 32 + quad * 8];
            acc = __builtin_amdgcn_mfma_f32_16x16x32_f16(a[kb], b, acc, 0, 0, 0);
        }
#pragma unroll
        for (int reg = 0; reg < 4; reg++) accs[ct][reg] = acc[reg] * di[reg];
    }

    // fp8 epilogue: stage 64x128 bytes in LDS (reuse Xl), then coalesced 16B stores
    __syncthreads();
    unsigned char* S = (unsigned char*)Xl;
#pragma unroll
    for (int ct = 0; ct < 8; ct++)
#pragma unroll
        for (int reg = 0; reg < 4; reg++) {
            int p = __builtin_amdgcn_cvt_pk_fp8_f32(accs[ct][reg], accs[ct][reg], 0, false);
            S[(w * 16 + quad * 4 + reg) * 128 + ct * 16 + l16] = (unsigned char)p;
        }
    __syncthreads();
#pragma unroll
    for (int i = 0; i < 2; i++) {
        int idx = tid + 256 * i;
        int r = idx >> 3, cg = idx & 7;
        if (row0 + r < N_NODES)
            ((uint4*)(h + (size_t)(row0 + r) * 128))[cg] = ((const uint4*)S)[idx];
    }
}

// ======== shared gather core: LDS-staged indices, 2-group double-buffered loads ========
// Requires in scope: H8, sidx, hw, l32, nc, jmax, dself. Produces accv[0..3].
#define AGG_ISSUE(buf, g) do {                                                             \
    unsigned int iw0 = *(const unsigned int*)&sidx[hw][(g) * 8 + 0];                       \
    unsigned int iw1 = *(const unsigned int*)&sidx[hw][(g) * 8 + 2];                       \
    unsigned int iw2 = *(const unsigned int*)&sidx[hw][(g) * 8 + 4];                       \
    unsigned int iw3 = *(const unsigned int*)&sidx[hw][(g) * 8 + 6];                       \
    buf[0] = *(const unsigned int*)(H8 + (size_t)(iw0 & 0xffffu) * 128 + l32 * 4);         \
    buf[1] = *(const unsigned int*)(H8 + (size_t)(iw0 >> 16) * 128 + l32 * 4);             \
    buf[2] = *(const unsigned int*)(H8 + (size_t)(iw1 & 0xffffu) * 128 + l32 * 4);         \
    buf[3] = *(const unsigned int*)(H8 + (size_t)(iw1 >> 16) * 128 + l32 * 4);             \
    buf[4] = *(const unsigned int*)(H8 + (size_t)(iw2 & 0xffffu) * 128 + l32 * 4);         \
    buf[5] = *(const unsigned int*)(H8 + (size_t)(iw2 >> 16) * 128 + l32 * 4);             \
    buf[6] = *(const unsigned int*)(H8 + (size_t)(iw3 & 0xffffu) * 128 + l32 * 4);         \
    buf[7] = *(const unsigned int*)(H8 + (size_t)(iw3 >> 16) * 128 + l32 * 4);             \
} while (0)

#define AGG_CONSUME(buf, g) do {                                                           \
    _Pragma("unroll")                                                                      \
    for (int i_ = 0; i_ < 8; i_++) {                                                       \
        float wt = ((g) * 8 + i_ < nc) ? 1.0f : 0.0f;                                      \
        f32x2 lo = __builtin_amdgcn_cvt_pk_f32_fp8((int)buf[i_], false);                   \
        f32x2 hi = __builtin_amdgcn_cvt_pk_f32_fp8((int)buf[i_], true);                    \
        accv[i_ & 3].x = fmaf(wt, lo[0], accv[i_ & 3].x);                                  \
        accv[i_ & 3].y = fmaf(wt, lo[1], accv[i_ & 3].y);                                  \
        accv[i_ & 3].z = fmaf(wt, hi[0], accv[i_ & 3].z);                                  \
        accv[i_ & 3].w = fmaf(wt, hi[1], accv[i_ & 3].w);                                  \
    }                                                                                      \
} while (0)

#define AGG_CORE()                                                                         \
    float4 accv[4];                                                                        \
    {                                                                                      \
        f32x2 lo = __builtin_amdgcn_cvt_pk_f32_fp8((int)dself, false);                     \
        f32x2 hi = __builtin_amdgcn_cvt_pk_f32_fp8((int)dself, true);                      \
        accv[0] = make_float4(lo[0], lo[1], hi[0], hi[1]);                                 \
    }                                                                                      \
    accv[1] = make_float4(0.f, 0.f, 0.f, 0.f); accv[2] = accv[1]; accv[3] = accv[1];       \
    unsigned int b0_[8], b1_[8];                                                           \
    AGG_ISSUE(b0_, 0);                                                                     \
    if (jmax > 8) { AGG_ISSUE(b1_, 1); }                                                   \
    AGG_CONSUME(b0_, 0);                                                                   \
    if (jmax > 8) {                                                                        \
        if (jmax > 16) { AGG_ISSUE(b0_, 2); }                                              \
        AGG_CONSUME(b1_, 1);                                                               \
        if (jmax > 16) {                                                                   \
            if (jmax > 24) { AGG_ISSUE(b1_, 3); }                                          \
            AGG_CONSUME(b0_, 2);                                                           \
            if (jmax > 24) { AGG_CONSUME(b1_, 3); }                                        \
        }                                                                                  \
    }

// ---------------- ELL aggregation (layer 0): pipelined gather, writes fp16 ACT ----------------
// 1-D grid, branch = blockIdx.x & 1 (pins each branch to one XCD parity for L2 locality)
__global__ __launch_bounds__(256) void k_agg(const int* __restrict__ cnti, const unsigned short* __restrict__ ell,
                                             const int2* __restrict__ ovf, const int* __restrict__ ocnt,
                                             const unsigned char* __restrict__ H8all, const float* __restrict__ bias1,
                                             const float* __restrict__ bias2, __half* __restrict__ ACT) {
    const int tid = threadIdx.x;
    const int l32 = tid & 31;
    const int hw = tid >> 5;
    const int br = blockIdx.x & 1;
    const int blk = blockIdx.x >> 1;
    const int node = blk * 8 + hw;

    const int* __restrict__ cnt = cnti + br * NPAD;
    const unsigned short* __restrict__ el = ell + (size_t)br * NPAD * ELLW;
    const int2* __restrict__ ov = ovf + (size_t)br * OVF_CAP;
    const unsigned char* __restrict__ H8 = H8all + (size_t)br * N_NODES * 128;
    const float* __restrict__ bias = (br ? bias2 : bias1);
    __half* __restrict__ out = ACT + (size_t)br * N_NODES * D;

    __shared__ unsigned short sidx[8][ELLW];
    if (tid < 32) ((uint4*)sidx)[tid] = ((const uint4*)(el + (size_t)blk * 8 * ELLW))[tid];

    int n = cnt[node];
    int nc = min(n, ELLW);
    int ncO = __shfl(nc, (tid & 63) ^ 32, 64);
    int jmax = max(nc, ncO);
    unsigned int dself = *(const unsigned int*)(H8 + (size_t)node * 128 + l32 * 4);
    __syncthreads();

    AGG_CORE();

    if (n > ELLW) {  // rare overflow path
        int oc = min(ocnt[br], OVF_CAP);
        for (int o = 0; o < oc; o++) {
            int2 p = ov[o];
            if (p.x == node) {
                unsigned int dw = *(const unsigned int*)(H8 + (size_t)p.y * 128 + l32 * 4);
                f32x2 lo = __builtin_amdgcn_cvt_pk_f32_fp8((int)dw, false);
                f32x2 hi = __builtin_amdgcn_cvt_pk_f32_fp8((int)dw, true);
                accv[0].x += lo[0]; accv[0].y += lo[1]; accv[0].z += hi[0]; accv[0].w += hi[1];
            }
        }
    }
    float sx = (accv[0].x + accv[1].x) + (accv[2].x + accv[3].x);
    float sy = (accv[0].y + accv[1].y) + (accv[2].y + accv[3].y);
    float sz = (accv[0].z + accv[1].z) + (accv[2].z + accv[3].z);
    float sw = (accv[0].w + accv[1].w) + (accv[2].w + accv[3].w);
    float dv = rsqrtf((float)n + 1.0f);
    float4 b = ((const float4*)bias)[l32];
    float vx = sx * dv + b.x;
    float vy = sy * dv + b.y;
    float vz = sz * dv + b.z;
    float vw = sw * dv + b.w;
    vx = vx > 0.0f ? vx : NEG_SLOPE * vx;
    vy = vy > 0.0f ? vy : NEG_SLOPE * vy;
    vz = vz > 0.0f ? vz : NEG_SLOPE * vz;
    vw = vw > 0.0f ? vw : NEG_SLOPE * vw;
    union { __half2 h2[2]; uint2 u; } up;
    up.h2[0] = __floats2half2_rn(vx, vy);
    up.h2[1] = __floats2half2_rn(vz, vw);
    *(uint2*)(out + (size_t)node * 128 + l32 * 4) = up.u;
}

// ---------------- fused agg(layer1) + mean pool: pipelined gather + segmented reduce ----------------
__global__ __launch_bounds__(256) void k_aggpool(const int* __restrict__ cnti, const unsigned short* __restrict__ ell,
                                                 const int2* __restrict__ ovf, const int* __restrict__ ocnt,
                                                 const unsigned char* __restrict__ H8all,
                                                 const float* __restrict__ bias1, const float* __restrict__ bias2,
                                                 const int* __restrict__ batch1, const int* __restrict__ batch2,
                                                 float* __restrict__ ppall) {
    const int tid = threadIdx.x;
    const int l32 = tid & 31;
    const int hw = tid >> 5;
    const int br = blockIdx.x & 1;
    const int blk = blockIdx.x >> 1;
    const int node = blk * 8 + hw;

    const int* __restrict__ cnt = cnti + br * NPAD;
    const unsigned short* __restrict__ el = ell + (size_t)br * NPAD * ELLW;
    const int2* __restrict__ ov = ovf + (size_t)br * OVF_CAP;
    const unsigned char* __restrict__ H8 = H8all + (size_t)br * N_NODES * 128;
    const float* __restrict__ bias = (br ? bias2 : bias1);
    const int* __restrict__ batch = (br ? batch2 : batch1);
    float* __restrict__ pp = ppall + (size_t)br * N_GRAPHS * D;

    __shared__ unsigned short sidx[8][ELLW];
    if (tid < 32) ((uint4*)sidx)[tid] = ((const uint4*)(el + (size_t)blk * 8 * ELLW))[tid];

    int n = cnt[node];
    int nc = min(n, ELLW);
    int ncO = __shfl(nc, (tid & 63) ^ 32, 64);
    int jmax = max(nc, ncO);
    unsigned int dself = *(const unsigned int*)(H8 + (size_t)node * 128 + l32 * 4);
    __syncthreads();

    AGG_CORE();

    if (n > ELLW) {  // rare overflow path
        int oc = min(ocnt[br], OVF_CAP);
        for (int o = 0; o < oc; o++) {
            int2 p = ov[o];
            if (p.x == node) {
                unsigned int dw = *(const unsigned int*)(H8 + (size_t)p.y * 128 + l32 * 4);
                f32x2 lo = __builtin_amdgcn_cvt_pk_f32_fp8((int)dw, false);
                f32x2 hi = __builtin_amdgcn_cvt_pk_f32_fp8((int)dw, true);
                accv[0].x += lo[0]; accv[0].y += lo[1]; accv[0].z += hi[0]; accv[0].w += hi[1];
            }
        }
    }
    float sx = (accv[0].x + accv[1].x) + (accv[2].x + accv[3].x);
    float sy = (accv[0].y + accv[1].y) + (accv[2].y + accv[3].y);
    float sz = (accv[0].z + accv[1].z) + (accv[2].z + accv[3].z);
    float sw = (accv[0].w + accv[1].w) + (accv[2].w + accv[3].w);
    float dv = rsqrtf((float)n + 1.0f);
    float4 b = ((const float4*)bias)[l32];
    float vx = sx * dv + b.x;
    float vy = sy * dv + b.y;
    float vz = sz * dv + b.z;
    float vw = sw * dv + b.w;
    vx = vx > 0.0f ? vx : NEG_SLOPE * vx;
    vy = vy > 0.0f ? vy : NEG_SLOPE * vy;
    vz = vz > 0.0f ? vz : NEG_SLOPE * vz;
    vw = vw > 0.0f ? vw : NEG_SLOPE * vw;
    // round to fp16 to preserve the old ACT numeric path
    __half2 q0 = __floats2half2_rn(vx, vy);
    __half2 q1 = __floats2half2_rn(vz, vw);
    float2 f0 = __half22float2(q0);
    float2 f1 = __half22float2(q1);

    __shared__ float sacc[8][128];
    __shared__ int sg[8];
    *(float4*)&sacc[hw][l32 * 4] = make_float4(f0.x, f0.y, f1.x, f1.y);
    if (l32 == 0) sg[hw] = batch[node];
    __syncthreads();
    if (tid < 128) {  // segmented reduction over the 8 (batch-sorted) nodes
        float s = sacc[0][tid];
        int g = sg[0];
        for (int r2 = 1; r2 < 8; r2++) {
            if (sg[r2] == g) {
                s += sacc[r2][tid];
            } else {
                atomicAdd(&pp[(size_t)g * D + tid], s);
                s = sacc[r2][tid];
                g = sg[r2];
            }
        }
        atomicAdd(&pp[(size_t)g * D + tid], s);
    }
}

// ---------------- final MLP ----------------
__global__ __launch_bounds__(128) void k_mlp(const float* __restrict__ pp, const int* __restrict__ cntg,
                                             const float* __restrict__ lin1W, const float* __restrict__ lin1b,
                                             const float* __restrict__ lin2W, const float* __restrict__ lin2b,
                                             float* __restrict__ out) {
    int g = blockIdx.x;
    int c = threadIdx.x;
    __shared__ float cat[2 * D];
    cat[c] = pp[(size_t)g * D + c] / fmaxf((float)cntg[g], 1.0f);
    cat[c + D] = pp[(size_t)(N_GRAPHS + g) * D + c] / fmaxf((float)cntg[64 + g], 1.0f);
    __syncthreads();
    float acc = lin1b[c];
#pragma unroll 8
    for (int k = 0; k < 2 * D; k++) acc += cat[k] * lin1W[k * D + c];
    acc = fmaxf(acc, 0.0f);
    float v = acc * lin2W[c];
#pragma unroll
    for (int off = 32; off > 0; off >>= 1) v += __shfl_down(v, off, 64);
    __shared__ float wsum[2];
    if ((c & 63) == 0) wsum[c >> 6] = v;
    __syncthreads();
    if (c == 0) out[g] = wsum[0] + wsum[1] + lin2b[0];
}

extern "C" void kernel_launch(void* const* d_in, const int* in_sizes, int n_in,
                              void* d_out, int out_size, void* d_ws, size_t ws_size,
                              hipStream_t stream) {
    const float* x1 = (const float*)d_in[0];
    const int*   ei1 = (const int*)d_in[1];
    const int*   batch1 = (const int*)d_in[2];
    const float* x2 = (const float*)d_in[3];
    const int*   ei2 = (const int*)d_in[4];
    const int*   batch2 = (const int*)d_in[5];
    const float* W1_0 = (const float*)d_in[6];
    const float* b1_0 = (const float*)d_in[7];
    const float* W1_1 = (const float*)d_in[8];
    const float* b1_1 = (const float*)d_in[9];
    const float* W2_0 = (const float*)d_in[10];
    const float* b2_0 = (const float*)d_in[11];
    const float* W2_1 = (const float*)d_in[12];
    const float* b2_1 = (const float*)d_in[13];
    const float* lin1W = (const float*)d_in[14];
    const float* lin1b = (const float*)d_in[15];
    const float* lin2W = (const float*)d_in[16];
    const float* lin2b = (const float*)d_in[17];
    float* out = (float*)d_out;

    // ---- workspace layout ----
    __half* WtH = (__half*)d_ws;                                          // 65536 halves (128 KB)
    __half* ACT = WtH + 65536;                                            // 2 * N*D halves
    unsigned char* H8a = (unsigned char*)(ACT + 2 * (size_t)N_NODES * D); // 2 * N*128 bytes
    unsigned char* H8b = H8a + 2 * (size_t)N_NODES * 128;                 // 2 * N*128 bytes
    unsigned short* ell = (unsigned short*)(H8b + 2 * (size_t)N_NODES * 128);  // 2 * NPAD*ELLW
    int2*   bucketed = (int2*)(ell + 2 * (size_t)NPAD * ELLW);            // 2 * BUCKETS*BCAP
    int*    cnti = (int*)(bucketed + 2 * (size_t)BUCKETS * BCAP);         // 2 * NPAD
    int*    gcnt = cnti + 2 * NPAD;                                       // 2 * BUCKETS (+ ocnt[8] contiguous)
    int*    ocnt = gcnt + 2 * BUCKETS;                                    // 8
    int*    cntg = ocnt + 8;                                              // 128
    int2*   ovf  = (int2*)(cntg + 128);                                   // 2 * OVF_CAP
    float*  pp   = (float*)(ovf + 2 * (size_t)OVF_CAP);                   // 2 * G * D

    dim3 b256(256);
    int partBlocks = (N_EDGES + EPB - 1) / EPB;  // 391 per branch
    int gemmBlocks = (N_NODES + 63) / 64;        // 782
    int aggBlocks  = N_NODES / 8;                // 6250 per branch

    k_prep<<<4, b256, 0, stream>>>(W1_0, W1_1, W2_0, W2_1, batch1, batch2, WtH, gcnt, pp, cntg);

    k_part  <<<partBlocks * 2, b256, 0, stream>>>(ei1, ei2, gcnt, bucketed);
    k_build <<<BUCKETS * 2,    b256, 0, stream>>>(gcnt, bucketed, cnti, ell, ovf, ocnt);

    k_gemm<false><<<dim3(gemmBlocks, 2), b256, 0, stream>>>(x1, x2, WtH, 0, cnti, H8a);
    k_agg        <<<aggBlocks * 2,       b256, 0, stream>>>(cnti, ell, ovf, ocnt, H8a, b1_0, b2_0, ACT);
    k_gemm<true> <<<dim3(gemmBlocks, 2), b256, 0, stream>>>(ACT, ACT + (size_t)N_NODES * D, WtH, 1, cnti, H8b);
    k_aggpool    <<<aggBlocks * 2,       b256, 0, stream>>>(cnti, ell, ovf, ocnt, H8b, b1_1, b2_1, batch1, batch2, pp);

    k_mlp<<<N_GRAPHS, dim3(128), 0, stream>>>(pp, cntg, lin1W, lin1b, lin2W, lin2b, out);
}